// Round 10
// baseline (181.465 us; speedup 1.0000x reference)
//
#include <hip/hip_runtime.h>
#include <hip/hip_bf16.h>

#define NB 32
#define NL 100
#define ND 128
#define NH 8
#define NE 64
#define NC 16

// scratch layout (float offsets into g_ws)
#define WS_WFT  16384    // 128*128 transposed ffn_w (f32)
#define WS_XI   33280    // B*L*H dest scores
#define WS_XJ   58880    // B*L*H src scores
#define WS_XP   84480    // B*L*128 projected x (f32)
#define WS_ES   (84480 + NB * NL * ND)          // B*L*L*H edge scores
#define WS_TOT  (WS_ES + NB * NL * NL * NH)

__device__ float g_ws[WS_TOT];

static __device__ __forceinline__ float pick8(const float* a, int c) {
    return (c < 4)
        ? ((c < 2) ? (c == 0 ? a[0] : a[1]) : (c == 2 ? a[2] : a[3]))
        : ((c < 6) ? (c == 4 ? a[4] : a[5]) : (c == 6 ? a[6] : a[7]));
}

// ================= mega3: xproj | wft | escore — single launch, no prep =================
// blocks [0,400):    xproj, 8 rows/block, Wx read directly (lane-decomposed)
// blocks [400,416):  ffn_w transpose -> f32 WfT (consumed only by gat_main)
// blocks [416,2048): escore, local proj from att_e·We, grid-stride over 40000 chunks
// total 2048 blocks = fully co-resident at 8 blocks/CU.
__global__ __launch_bounds__(256) void mega3_kernel(
        const float* __restrict__ x, const float* __restrict__ e,
        const float* __restrict__ Wx, const float* __restrict__ We,
        const float* __restrict__ att_src, const float* __restrict__ att_dst,
        const float* __restrict__ att_e, const float* __restrict__ ffn_w) {
    __shared__ float smem[2048];   // 8 KB
    int blk = blockIdx.x;
    int t = threadIdx.x;

    if (blk < 400) {
        // ---------------- xproj: 8 rows per block, direct Wx ----------------
        int bl0 = blk * 8;
        float* xrowL = smem;           // [8][128]
        float* xpL   = smem + 1024;    // [8][128]
        ((float4*)xrowL)[t] = ((const float4*)(x + bl0 * 128))[t];  // 8 rows
        __syncthreads();
        int lane = t & 63, w = t >> 6;
        int d_sub = lane >> 3, c_sub = lane & 7;
        const float4* Wx4 = (const float4*)Wx;
        #pragma unroll
        for (int rr = 0; rr < 4; ++rr) {
            int d = rr * 32 + w * 8 + d_sub;
            float4 wc0 = Wx4[d * 32 + c_sub * 4 + 0];
            float4 wc1 = Wx4[d * 32 + c_sub * 4 + 1];
            float4 wc2 = Wx4[d * 32 + c_sub * 4 + 2];
            float4 wc3 = Wx4[d * 32 + c_sub * 4 + 3];
            float accs[8];
            #pragma unroll
            for (int r = 0; r < 8; ++r) {
                const float4* xr = (const float4*)(xrowL + r * 128);
                float4 a0 = xr[c_sub * 4 + 0], a1 = xr[c_sub * 4 + 1];
                float4 a2 = xr[c_sub * 4 + 2], a3 = xr[c_sub * 4 + 3];
                accs[r] = wc0.x * a0.x + wc0.y * a0.y + wc0.z * a0.z + wc0.w * a0.w
                        + wc1.x * a1.x + wc1.y * a1.y + wc1.z * a1.z + wc1.w * a1.w
                        + wc2.x * a2.x + wc2.y * a2.y + wc2.z * a2.z + wc2.w * a2.w
                        + wc3.x * a3.x + wc3.y * a3.y + wc3.z * a3.z + wc3.w * a3.w;
            }
            #pragma unroll
            for (int st = 1; st < 8; st <<= 1)
                #pragma unroll
                for (int r = 0; r < 8; ++r)
                    accs[r] += __shfl_xor(accs[r], st);
            float v = pick8(accs, c_sub);       // lane c_sub owns row bl0+c_sub, col d
            xpL[c_sub * 128 + d] = v;
            g_ws[WS_XP + (bl0 + c_sub) * 128 + d] = v;
        }
        __syncthreads();
        // per-head attention scores from LDS xp
        {
            int r = t >> 5, sub = t & 31;
            int h = sub >> 2;
            float sp = 0.f, sd = 0.f;
            #pragma unroll
            for (int q = 0; q < 4; ++q) {
                float xv = xpL[r * 128 + sub * 4 + q];
                sp += xv * att_src[sub * 4 + q];
                sd += xv * att_dst[sub * 4 + q];
            }
            sp += __shfl_xor(sp, 1); sp += __shfl_xor(sp, 2);
            sd += __shfl_xor(sd, 1); sd += __shfl_xor(sd, 2);
            if ((sub & 3) == 0) {
                g_ws[WS_XJ + (bl0 + r) * 8 + h] = sp;
                g_ws[WS_XI + (bl0 + r) * 8 + h] = sd;
            }
        }
    } else if (blk < 416) {
        // ---------------- wft: transpose ffn_w -> f32 WfT ----------------
        int r0 = (blk - 400) * 8;           // 8 d-rows of ffn_w
        float* tileL = smem;                // [8][128]
        int k = t & 127, rh = t >> 7;
        #pragma unroll
        for (int ri = 0; ri < 4; ++ri) {
            int rr = ri * 2 + rh;
            tileL[rr * 128 + k] = ffn_w[(r0 + rr) * 128 + k];
        }
        __syncthreads();
        if (t < 128) {
            float4 p0, p1;
            p0.x = tileL[0 * 128 + t]; p0.y = tileL[1 * 128 + t];
            p0.z = tileL[2 * 128 + t]; p0.w = tileL[3 * 128 + t];
            p1.x = tileL[4 * 128 + t]; p1.y = tileL[5 * 128 + t];
            p1.z = tileL[6 * 128 + t]; p1.w = tileL[7 * 128 + t];
            float4* dst = (float4*)(g_ws + WS_WFT + t * 128 + r0);
            dst[0] = p0;
            dst[1] = p1;
        }
    } else {
        // ---------------- escore: local proj + stream e ----------------
        float* projL = smem;                // [8][64]
        for (int pid = t; pid < 512; pid += 256) {
            int h = pid >> 6, eix = pid & 63;
            float acc = 0.f;
            #pragma unroll
            for (int c = 0; c < NC; ++c)
                acc += att_e[h * NC + c] * We[(h * NC + c) * NE + eix];
            projL[pid] = acc;
        }
        __syncthreads();
        int lane = t & 63;
        int j_sub = lane >> 3, c_sub = lane & 7;
        const float4* projL4 = (const float4*)projL;
        float4 p4[16];
        #pragma unroll
        for (int h = 0; h < 8; ++h) {
            p4[h * 2]     = projL4[h * 16 + c_sub * 2];
            p4[h * 2 + 1] = projL4[h * 16 + c_sub * 2 + 1];
        }
        const float4* e4 = (const float4*)e;
        int wid = (blk - 416) * 4 + (t >> 6);
        const int nw = 1632 * 4;
        for (int chunk = wid; chunk < NB * NL * NL / 8; chunk += nw) {
            long rid = (long)chunk * 8 + j_sub;
            float4 ev0 = e4[rid * 16 + c_sub * 2];
            float4 ev1 = e4[rid * 16 + c_sub * 2 + 1];
            float part[8];
            #pragma unroll
            for (int h = 0; h < 8; ++h) {
                float4 a = p4[h * 2], bq = p4[h * 2 + 1];
                part[h] = ev0.x * a.x + ev0.y * a.y + ev0.z * a.z + ev0.w * a.w
                        + ev1.x * bq.x + ev1.y * bq.y + ev1.z * bq.z + ev1.w * bq.w;
            }
            #pragma unroll
            for (int st = 1; st < 8; st <<= 1)
                #pragma unroll
                for (int h = 0; h < 8; ++h)
                    part[h] += __shfl_xor(part[h], st);
            g_ws[WS_ES + rid * 8 + c_sub] = pick8(part, c_sub);
        }
    }
}

// ---------------------------------------------------------------- gat_main: 2 i/block, all f32 (round-5 proven)
__global__ __launch_bounds__(256) void gat_main(
        const int* __restrict__ adj, const float* __restrict__ ffn_b,
        const float* __restrict__ ln_g, const float* __restrict__ ln_b,
        float* __restrict__ out) {
    __shared__ float s_lds[2][NL * 9];       // scores/alpha, stride 9 (conflict-free)
    __shared__ float partL[2][2][128];
    __shared__ float rowL[2][128];
    __shared__ float hvalL[2][128];
    __shared__ float inv[2][8];
    __shared__ float mr[2][2];

    int blk = blockIdx.x;
    int b = blk / 50, i0 = (blk % 50) * 2;
    int t = threadIdx.x;
    const float* xp = g_ws + WS_XP;

    // phase 1: scores for 2 i
    {
        int h = t & 7, jj = t >> 3;
        #pragma unroll
        for (int ii = 0; ii < 2; ++ii) {
            int bi = b * NL + i0 + ii;
            float xiv = g_ws[WS_XI + bi * 8 + h];
            #pragma unroll
            for (int r = 0; r < 4; ++r) {
                int j = jj + r * 32;
                if (j < NL) {
                    float s = xiv + g_ws[WS_XJ + (b * NL + j) * 8 + h]
                            + g_ws[WS_ES + ((long)bi * NL + j) * 8 + h];
                    s = s > 0.f ? s : 0.2f * s;
                    s = adj[bi * NL + j] ? s : -1e9f;
                    s_lds[ii][j * 9 + h] = s;
                }
            }
        }
    }
    __syncthreads();
    // phase 2: softmax over j per (ii,h)
    {
        int h = t >> 5, jt = t & 31;
        const float LOG2E = 1.44269504f;
        #pragma unroll
        for (int ii = 0; ii < 2; ++ii) {
            float* sl = s_lds[ii];
            float v0 = sl[jt * 9 + h];
            float v1 = sl[(jt + 32) * 9 + h];
            float v2 = sl[(jt + 64) * 9 + h];
            float v3 = (jt < 4) ? sl[(jt + 96) * 9 + h] : -3.0e38f;
            float m = fmaxf(fmaxf(v0, v1), fmaxf(v2, v3));
            #pragma unroll
            for (int st = 1; st < 32; st <<= 1) m = fmaxf(m, __shfl_xor(m, st));
            float p0 = exp2f((v0 - m) * LOG2E);
            float p1 = exp2f((v1 - m) * LOG2E);
            float p2 = exp2f((v2 - m) * LOG2E);
            float p3 = (jt < 4) ? exp2f((v3 - m) * LOG2E) : 0.f;
            float sum = p0 + p1 + p2 + p3;
            #pragma unroll
            for (int st = 1; st < 32; st <<= 1) sum += __shfl_xor(sum, st);
            sl[jt * 9 + h] = p0;
            sl[(jt + 32) * 9 + h] = p1;
            sl[(jt + 64) * 9 + h] = p2;
            if (jt < 4) sl[(jt + 96) * 9 + h] = p3;
            if (jt == 0) inv[ii][h] = 1.0f / sum;
        }
    }
    __syncthreads();
    // phase 3: aggregation — one xp read serves 2 i
    {
        int d = t & 127, half = t >> 7, hh = d >> 4;
        float a0 = 0.f, a1 = 0.f;
        int j0 = half * 50;
        #pragma unroll 5
        for (int k = 0; k < 50; ++k) {
            int j = j0 + k;
            float xv = xp[(b * NL + j) * 128 + d];
            a0 = fmaf(s_lds[0][j * 9 + hh], xv, a0);
            a1 = fmaf(s_lds[1][j * 9 + hh], xv, a1);
        }
        partL[half][0][d] = a0;
        partL[half][1][d] = a1;
    }
    __syncthreads();
    {
        int d = t & 127, ii = t >> 7;
        rowL[ii][d] = (partL[0][ii][d] + partL[1][ii][d]) * inv[ii][d >> 4];
    }
    __syncthreads();
    // phase 4: FFN — one WfT read serves 2 rows
    {
        int d = t & 127, half = t >> 7;
        const float* WfT = g_ws + WS_WFT;
        float a0 = 0.f, a1 = 0.f;
        int k0 = half * 64;
        #pragma unroll 8
        for (int k = k0; k < k0 + 64; ++k) {
            float wv = WfT[k * 128 + d];
            a0 = fmaf(wv, rowL[0][k], a0);
            a1 = fmaf(wv, rowL[1][k], a1);
        }
        partL[half][0][d] = a0;
        partL[half][1][d] = a1;
    }
    __syncthreads();
    {
        int d = t & 127, ii = t >> 7;
        hvalL[ii][d] = partL[0][ii][d] + partL[1][ii][d] + ffn_b[d];
    }
    __syncthreads();
    // phase 5: LayerNorm stats — wave 0 -> row 0, wave 1 -> row 1
    {
        int row = t >> 6, lane = t & 63;
        if (row < 2) {
            float a = hvalL[row][lane], b2 = hvalL[row][lane + 64];
            float s1 = a + b2, s2 = a * a + b2 * b2;
            #pragma unroll
            for (int st = 1; st < 64; st <<= 1) {
                s1 += __shfl_xor(s1, st);
                s2 += __shfl_xor(s2, st);
            }
            if (lane == 0) {
                float mu = s1 * (1.0f / 128.0f);
                float var = s2 * (1.0f / 128.0f) - mu * mu;
                mr[row][0] = mu;
                mr[row][1] = rsqrtf(var + 1e-5f);
            }
        }
    }
    __syncthreads();
    {
        int d = t & 127, ii = t >> 7;
        float y = (hvalL[ii][d] - mr[ii][0]) * mr[ii][1] * ln_g[d] + ln_b[d];
        out[(b * NL + i0 + ii) * 128 + d] = fmaxf(y, 0.f);
    }
}

// ---------------------------------------------------------------- launch
extern "C" void kernel_launch(void* const* d_in, const int* in_sizes, int n_in,
                              void* d_out, int out_size, void* d_ws, size_t ws_size,
                              hipStream_t stream) {
    const float* x       = (const float*)d_in[0];
    const int*   adj     = (const int*)  d_in[1];
    const float* e       = (const float*)d_in[2];
    const float* Wx      = (const float*)d_in[3];
    const float* We      = (const float*)d_in[4];
    const float* att_src = (const float*)d_in[5];
    const float* att_dst = (const float*)d_in[6];
    const float* att_e   = (const float*)d_in[7];
    const float* ffn_w   = (const float*)d_in[8];
    const float* ffn_b   = (const float*)d_in[9];
    const float* ln_g    = (const float*)d_in[10];
    const float* ln_b    = (const float*)d_in[11];
    float* out = (float*)d_out;

    hipLaunchKernelGGL(mega3_kernel, dim3(2048), dim3(256), 0, stream,
                       x, e, Wx, We, att_src, att_dst, att_e, ffn_w);
    hipLaunchKernelGGL(gat_main, dim3(NB * 50), dim3(256), 0, stream,
                       adj, ffn_b, ln_g, ln_b, out);
}